// Round 11
// baseline (236.725 us; speedup 1.0000x reference)
//
#include <hip/hip_runtime.h>

// Problem constants (B=8, N=8192, C=256, K=8, nblocks=8, blk=32)
#define NPTS 8192
#define CH   256
#define KNB  8
#define NROWS 65536        // B*N
#define RPB_S1 32
#define NBLK_CONV 8192     // NROWS*CH/(256*8)
#define NBLK_S1   (NROWS / RPB_S1)   // 2048
#define NBLK_S2   (NROWS / 16)       // 4096

// LDS strides chosen for bank spread (non-128B-multiple rows, non-64B l-stride)
#define S1_STRIDE 544      // s1 blend buffer / t staging: 32 x 544 = 17,408 B
#define FS_STRIDE 656      // f buffer row stride:          32 x 656 = 20,992 B
#define FS_L      80       // f l-stride (8 l x 80 B; r*2 <= 64 < 80)

typedef unsigned short ushort_t;
typedef float  f32x4  __attribute__((ext_vector_type(4)));   // nontemporal + MFMA C/D
typedef short  bf16x8 __attribute__((ext_vector_type(8)));   // MFMA A/B frag (8 bf16)

// Raw barrier: LDS ordering only; global loads stay in flight across it.
#define BARRIER_LDS() do { \
    asm volatile("s_waitcnt lgkmcnt(0)" ::: "memory"); \
    __builtin_amdgcn_s_barrier(); \
} while (0)

// Scheduling fence: stops LLVM from SINKING issued loads to just-before-use
// (R10 counters: stage2 VGPR=36 proved the "issue everything" pipeline was
// being rescheduled into per-row load/use pairs -> 1 row in flight -> 45% BW).
#define SCHED_FENCE() __builtin_amdgcn_sched_barrier(0)

// XCD-aware swizzle: 8 batches == 8 XCDs; XCD i owns batch i (4 MB slice in L2).
__device__ __forceinline__ int xcd_swz(int h, int cpx) {
    return (h & 7) * cpx + (h >> 3);     // bijective: grid % 8 == 0 everywhere
}

__device__ __forceinline__ ushort_t f32_to_bf16(float f) {
    unsigned int b = __float_as_uint(f);
    b += 0x7FFFu + ((b >> 16) & 1u);
    return (ushort_t)(b >> 16);
}
__device__ __forceinline__ float bf16_to_f32(ushort_t u) {
    return __uint_as_float(((unsigned int)u) << 16);
}
__device__ __forceinline__ unsigned int pack_bf16(float lo, float hi) {
    return (unsigned int)f32_to_bf16(lo) | ((unsigned int)f32_to_bf16(hi) << 16);
}
__device__ __forceinline__ bf16x8 pack8w(const float* __restrict__ p) {
    bf16x8 r;
#pragma unroll
    for (int j = 0; j < 8; ++j) r[j] = (short)f32_to_bf16(p[j]);
    return r;
}

// Swizzled LDS addressing: XOR row bits into 16B-slot bits (bits 4-6).
__device__ __forceinline__ unsigned char* s1addr(unsigned char* base, int row, int byte_off) {
    return base + row * S1_STRIDE + (byte_off ^ ((row & 7) << 4));
}
__device__ __forceinline__ unsigned char* fsaddr(unsigned char* base, int row, int byte_off) {
    return base + row * FS_STRIDE + (byte_off ^ ((row & 7) << 4));
}

// ---------------------------------------------------------------------------
// Prepass: x fp32 -> bf16, XCD-pinned. (R10 verbatim)
// ---------------------------------------------------------------------------
__global__ __launch_bounds__(256) void pm_conv(
    const f32x4* __restrict__ x, uint4* __restrict__ xb)
{
    const int l = xcd_swz(blockIdx.x, NBLK_CONV / 8);
    const size_t i = (size_t)l * 256 + threadIdx.x;
    const f32x4 a = __builtin_nontemporal_load(&x[2 * i]);
    const f32x4 c = __builtin_nontemporal_load(&x[2 * i + 1]);
    uint4 o;
    o.x = pack_bf16(a.x, a.y);
    o.y = pack_bf16(a.z, a.w);
    o.z = pack_bf16(c.x, c.y);
    o.w = pack_bf16(c.z, c.w);
    xb[i] = o;
}

// ---------------------------------------------------------------------------
// Stage 1, MFMA edition v2 + sched-fenced phase-1 pipeline. (else R10)
// ---------------------------------------------------------------------------
__global__ __launch_bounds__(256, 4) void pm_stage1(
    const ushort_t* __restrict__ xb, const float* __restrict__ dist,
    const int* __restrict__ idx, const float* __restrict__ w1,
    const float* __restrict__ w2, const float* __restrict__ bias,
    ushort_t* __restrict__ t)
{
    const int lane = threadIdx.x & 63;
    const int wv   = __builtin_amdgcn_readfirstlane(threadIdx.x >> 6);

    __shared__ __align__(16) unsigned char s1b[RPB_S1 * S1_STRIDE];
    __shared__ __align__(16) unsigned char fsb[RPB_S1 * FS_STRIDE];

    const int lb       = xcd_swz(blockIdx.x, NBLK_S1 / 8);
    const int row_base = lb * RPB_S1;
    const int b        = row_base >> 13;           // batch == XCD id
    const char* xbase  = (const char*)(xb + (size_t)b * NPTS * CH);
    const int laneoff  = lane * 8;                 // 8 B per ushort4

#define LOAD_META(dd, nn, row) do {                                        \
    const float4 m0_ = *(const float4*)(dist + (size_t)(row) * KNB);       \
    const float4 m1_ = *(const float4*)(dist + (size_t)(row) * KNB + 4);   \
    const int4   j0_ = *(const int4*)(idx + (size_t)(row) * KNB);          \
    const int4   j1_ = *(const int4*)(idx + (size_t)(row) * KNB + 4);      \
    dd[0]=m0_.x; dd[1]=m0_.y; dd[2]=m0_.z; dd[3]=m0_.w;                    \
    dd[4]=m1_.x; dd[5]=m1_.y; dd[6]=m1_.z; dd[7]=m1_.w;                    \
    nn[0]=__builtin_amdgcn_readfirstlane(j0_.x);                           \
    nn[1]=__builtin_amdgcn_readfirstlane(j0_.y);                           \
    nn[2]=__builtin_amdgcn_readfirstlane(j0_.z);                           \
    nn[3]=__builtin_amdgcn_readfirstlane(j0_.w);                           \
    nn[4]=__builtin_amdgcn_readfirstlane(j1_.x);                           \
    nn[5]=__builtin_amdgcn_readfirstlane(j1_.y);                           \
    nn[6]=__builtin_amdgcn_readfirstlane(j1_.z);                           \
    nn[7]=__builtin_amdgcn_readfirstlane(j1_.w);                           \
} while (0)

#define ISSUE_G(cc, gg, nn, row) do {                                      \
    const int rloc_ = (row) & (NPTS - 1);                                  \
    cc = *(const ushort4*)(xbase + ((size_t)rloc_ << 9) + laneoff);        \
    _Pragma("unroll")                                                      \
    for (int k_ = 0; k_ < KNB; ++k_)                                       \
        gg[k_] = *(const ushort4*)(xbase + ((size_t)(unsigned)nn[k_] << 9) + laneoff); \
} while (0)

#define BLEND_W(cc, gg, dd, rl_) do {                                      \
    float mn_ = dd[0];                                                     \
    _Pragma("unroll")                                                      \
    for (int k_ = 1; k_ < KNB; ++k_) mn_ = fminf(mn_, dd[k_]);             \
    float e_[KNB]; float sum_ = 0.f;                                       \
    _Pragma("unroll")                                                      \
    for (int k_ = 0; k_ < KNB; ++k_) { e_[k_] = __expf(mn_ - dd[k_]); sum_ += e_[k_]; } \
    const float inv_ = 0.05f / sum_;                                       \
    float ax_ = 0.95f * bf16_to_f32(cc.x);                                 \
    float ay_ = 0.95f * bf16_to_f32(cc.y);                                 \
    float az_ = 0.95f * bf16_to_f32(cc.z);                                 \
    float aw_ = 0.95f * bf16_to_f32(cc.w);                                 \
    _Pragma("unroll")                                                      \
    for (int k_ = 0; k_ < KNB; ++k_) {                                     \
        const float w_ = e_[k_] * inv_;                                    \
        ax_ += w_ * bf16_to_f32(gg[k_].x);                                 \
        ay_ += w_ * bf16_to_f32(gg[k_].y);                                 \
        az_ += w_ * bf16_to_f32(gg[k_].z);                                 \
        aw_ += w_ * bf16_to_f32(gg[k_].w);                                 \
    }                                                                      \
    uint2 pv_;                                                             \
    pv_.x = pack_bf16(ax_, ay_);                                           \
    pv_.y = pack_bf16(az_, aw_);                                           \
    *(uint2*)s1addr(s1b, rl_, lane * 8) = pv_;                             \
} while (0)

    // ============ phase 1: blend, two-deep gather pipeline (sched-fenced) ==
    float dA[KNB], dB[KNB];
    int   nA[KNB], nB[KNB];
    ushort4 cA, gA[KNB], cB, gB[KNB];

    LOAD_META(dA, nA, row_base + wv);
    LOAD_META(dB, nB, row_base + 4 + wv);
    ISSUE_G(cA, gA, nA, row_base + wv);
    ISSUE_G(cB, gB, nB, row_base + 4 + wv);
    SCHED_FENCE();   // both sets must be in flight before any blend

#pragma unroll
    for (int p = 0; p < 8; ++p) {
        const int rl   = p * 4 + wv;
        const int rown = row_base + (p + 2) * 4 + wv;

        // raw meta prefetch for p+2 (in flight during the blend)
        float4 dn0, dn1; int4 in0, in1;
        if (p < 6) {
            dn0 = *(const float4*)(dist + (size_t)rown * KNB);
            dn1 = *(const float4*)(dist + (size_t)rown * KNB + 4);
            in0 = *(const int4*)(idx + (size_t)rown * KNB);
            in1 = *(const int4*)(idx + (size_t)rown * KNB + 4);
        }

        if ((p & 1) == 0) {
            BLEND_W(cA, gA, dA, rl);
            if (p < 6) {
                dA[0]=dn0.x; dA[1]=dn0.y; dA[2]=dn0.z; dA[3]=dn0.w;
                dA[4]=dn1.x; dA[5]=dn1.y; dA[6]=dn1.z; dA[7]=dn1.w;
                nA[0]=__builtin_amdgcn_readfirstlane(in0.x);
                nA[1]=__builtin_amdgcn_readfirstlane(in0.y);
                nA[2]=__builtin_amdgcn_readfirstlane(in0.z);
                nA[3]=__builtin_amdgcn_readfirstlane(in0.w);
                nA[4]=__builtin_amdgcn_readfirstlane(in1.x);
                nA[5]=__builtin_amdgcn_readfirstlane(in1.y);
                nA[6]=__builtin_amdgcn_readfirstlane(in1.z);
                nA[7]=__builtin_amdgcn_readfirstlane(in1.w);
                ISSUE_G(cA, gA, nA, rown);
            }
        } else {
            BLEND_W(cB, gB, dB, rl);
            if (p < 6) {
                dB[0]=dn0.x; dB[1]=dn0.y; dB[2]=dn0.z; dB[3]=dn0.w;
                dB[4]=dn1.x; dB[5]=dn1.y; dB[6]=dn1.z; dB[7]=dn1.w;
                nB[0]=__builtin_amdgcn_readfirstlane(in0.x);
                nB[1]=__builtin_amdgcn_readfirstlane(in0.y);
                nB[2]=__builtin_amdgcn_readfirstlane(in0.z);
                nB[3]=__builtin_amdgcn_readfirstlane(in0.w);
                nB[4]=__builtin_amdgcn_readfirstlane(in1.x);
                nB[5]=__builtin_amdgcn_readfirstlane(in1.y);
                nB[6]=__builtin_amdgcn_readfirstlane(in1.z);
                nB[7]=__builtin_amdgcn_readfirstlane(in1.w);
                ISSUE_G(cB, gB, nB, rown);
            }
        }
        SCHED_FENCE();   // issued loads may not sink into later iterations
    }
#undef LOAD_META
#undef ISSUE_G
#undef BLEND_W

    BARRIER_LDS();   // all 32 s1 rows visible

    // ============ phase 2: stage A via MFMA (wave wv: kb = 2wv, 2wv+1) =====
    const int l15 = lane & 15;
    const int kq  = lane >> 4;
#pragma unroll
    for (int kk = 0; kk < 2; ++kk) {
        const int kb = wv * 2 + kk;
        const int ao = kb * 64 + kq * 16;
        const bf16x8 a0 = *(const bf16x8*)s1addr(s1b, l15, ao);
        const bf16x8 a1 = *(const bf16x8*)s1addr(s1b, 16 + l15, ao);
        const bf16x8 b0 = pack8w(w1 + (size_t)(kb * 32 + l15) * 32 + kq * 8);
        const bf16x8 b1 = pack8w(w1 + (size_t)(kb * 32 + 16 + l15) * 32 + kq * 8);
        f32x4 d00 = {0.f,0.f,0.f,0.f}, d01 = d00, d10 = d00, d11 = d00;
        d00 = __builtin_amdgcn_mfma_f32_16x16x32_bf16(a0, b0, d00, 0, 0, 0);
        d01 = __builtin_amdgcn_mfma_f32_16x16x32_bf16(a0, b1, d01, 0, 0, 0);
        d10 = __builtin_amdgcn_mfma_f32_16x16x32_bf16(a1, b0, d10, 0, 0, 0);
        d11 = __builtin_amdgcn_mfma_f32_16x16x32_bf16(a1, b1, d11, 0, 0, 0);
#pragma unroll
        for (int nt = 0; nt < 2; ++nt) {
            const int qq = nt * 16 + l15;
            const int fo = (qq & 7) * FS_L + (kb * 4 + (qq >> 3)) * 2;
#pragma unroll
            for (int mt = 0; mt < 2; ++mt) {
                const f32x4 dd = (mt == 0) ? (nt == 0 ? d00 : d01)
                                           : (nt == 0 ? d10 : d11);
#pragma unroll
                for (int reg = 0; reg < 4; ++reg) {
                    const int row = mt * 16 + kq * 4 + reg;
                    *(ushort_t*)fsaddr(fsb, row, fo) = f32_to_bf16(dd[reg]);
                }
            }
        }
    }

    BARRIER_LDS();   // fs complete

    // ============ phase 3: stage B via MFMA, l2-pair packed output =========
    {
        const int l20 = wv * 2;
        const bf16x8 fa00 = *(const bf16x8*)fsaddr(fsb, l15,      l20 * FS_L + kq * 16);
        const bf16x8 fa01 = *(const bf16x8*)fsaddr(fsb, 16 + l15, l20 * FS_L + kq * 16);
        const bf16x8 fa10 = *(const bf16x8*)fsaddr(fsb, l15,      (l20 + 1) * FS_L + kq * 16);
        const bf16x8 fa11 = *(const bf16x8*)fsaddr(fsb, 16 + l15, (l20 + 1) * FS_L + kq * 16);
        const bf16x8 wb00 = pack8w(w2 + (size_t)(l20 * 32 + l15) * 32 + kq * 8);
        const bf16x8 wb01 = pack8w(w2 + (size_t)(l20 * 32 + 16 + l15) * 32 + kq * 8);
        const bf16x8 wb10 = pack8w(w2 + (size_t)((l20 + 1) * 32 + l15) * 32 + kq * 8);
        const bf16x8 wb11 = pack8w(w2 + (size_t)((l20 + 1) * 32 + 16 + l15) * 32 + kq * 8);
        f32x4 z = {0.f, 0.f, 0.f, 0.f};
        f32x4 D0m0n0 = __builtin_amdgcn_mfma_f32_16x16x32_bf16(fa00, wb00, z, 0, 0, 0);
        f32x4 D0m0n1 = __builtin_amdgcn_mfma_f32_16x16x32_bf16(fa00, wb01, z, 0, 0, 0);
        f32x4 D0m1n0 = __builtin_amdgcn_mfma_f32_16x16x32_bf16(fa01, wb00, z, 0, 0, 0);
        f32x4 D0m1n1 = __builtin_amdgcn_mfma_f32_16x16x32_bf16(fa01, wb01, z, 0, 0, 0);
        f32x4 D1m0n0 = __builtin_amdgcn_mfma_f32_16x16x32_bf16(fa10, wb10, z, 0, 0, 0);
        f32x4 D1m0n1 = __builtin_amdgcn_mfma_f32_16x16x32_bf16(fa10, wb11, z, 0, 0, 0);
        f32x4 D1m1n0 = __builtin_amdgcn_mfma_f32_16x16x32_bf16(fa11, wb10, z, 0, 0, 0);
        f32x4 D1m1n1 = __builtin_amdgcn_mfma_f32_16x16x32_bf16(fa11, wb11, z, 0, 0, 0);

#pragma unroll
        for (int nt = 0; nt < 2; ++nt) {
            const int q   = nt * 16 + l15;
            const float bv0 = bias[q * 8 + l20];
            const float bv1 = bias[q * 8 + l20 + 1];
#pragma unroll
            for (int mt = 0; mt < 2; ++mt) {
                const f32x4 e0 = (mt == 0) ? (nt == 0 ? D0m0n0 : D0m0n1)
                                           : (nt == 0 ? D0m1n0 : D0m1n1);
                const f32x4 e1 = (mt == 0) ? (nt == 0 ? D1m0n0 : D1m0n1)
                                           : (nt == 0 ? D1m1n0 : D1m1n1);
#pragma unroll
                for (int reg = 0; reg < 4; ++reg) {
                    const int row = mt * 16 + kq * 4 + reg;
                    *(unsigned int*)s1addr(s1b, row, q * 16 + wv * 4) =
                        pack_bf16(e0[reg] + bv0, e1[reg] + bv1);
                }
            }
        }
    }

    BARRIER_LDS();   // t staging complete

    // ============ phase 4: coalesced t writeout (wave wv: rows 8wv..+8) ====
#pragma unroll
    for (int r = 0; r < 8; ++r) {
        const int row = wv * 8 + r;
        const uint2 v = *(const uint2*)s1addr(s1b, row, lane * 8);
        *(uint2*)((char*)t + ((size_t)(row_base + row) << 9) + lane * 8) = v;
    }
}

// ---------------------------------------------------------------------------
// Stage 2: out = 0.95*t + 0.05*sum_k w_k*t[b,idx_k] + rf  (t bf16).
// Sched-fenced issue pipeline: meta loads first, then ALL 44 data loads
// (row-major so row 0 completes first), SCHED_FENCE so nothing sinks, then
// weight-compute overlaps the gather flight. (256,3): VGPR cap ~170 holds
// the ~130-reg in-flight set without spills.
// ---------------------------------------------------------------------------
__global__ __launch_bounds__(256, 3) void pm_stage2(
    const ushort_t* __restrict__ t, const float* __restrict__ dist,
    const int* __restrict__ idx, const float* __restrict__ rf,
    float* __restrict__ out)
{
    const int w     = __builtin_amdgcn_readfirstlane(threadIdx.x >> 6);
    const int lane  = threadIdx.x & 63;
    const int lb    = xcd_swz(blockIdx.x, NBLK_S2 / 8);
    const int wrow0 = lb * 16 + w * 4;
    const int b     = wrow0 >> 13;
    const char* tbase = (const char*)(t + (size_t)b * NPTS * CH);
    const int laneoff = lane * 8;

    // ---- phase A: meta loads (issued first -> complete first) ----
    int   nbs[4][KNB];
    float d [4][KNB];
#pragma unroll
    for (int r = 0; r < 4; ++r) {
        const int row = wrow0 + r;
        const float4 d0 = *(const float4*)(dist + (size_t)row * KNB);
        const float4 d1 = *(const float4*)(dist + (size_t)row * KNB + 4);
        const int4   i0 = *(const int4*)(idx + (size_t)row * KNB);
        const int4   i1 = *(const int4*)(idx + (size_t)row * KNB + 4);
        d[r][0]=d0.x; d[r][1]=d0.y; d[r][2]=d0.z; d[r][3]=d0.w;
        d[r][4]=d1.x; d[r][5]=d1.y; d[r][6]=d1.z; d[r][7]=d1.w;
        nbs[r][0]=__builtin_amdgcn_readfirstlane(i0.x);
        nbs[r][1]=__builtin_amdgcn_readfirstlane(i0.y);
        nbs[r][2]=__builtin_amdgcn_readfirstlane(i0.z);
        nbs[r][3]=__builtin_amdgcn_readfirstlane(i0.w);
        nbs[r][4]=__builtin_amdgcn_readfirstlane(i1.x);
        nbs[r][5]=__builtin_amdgcn_readfirstlane(i1.y);
        nbs[r][6]=__builtin_amdgcn_readfirstlane(i1.z);
        nbs[r][7]=__builtin_amdgcn_readfirstlane(i1.w);
    }

    // ---- phase B: issue ALL data loads, row-major ----
    ushort4 c0[4], g[4][KNB];
    f32x4   rv[4];
#pragma unroll
    for (int r = 0; r < 4; ++r) {
        const int rloc = (wrow0 + r) & (NPTS - 1);
        c0[r] = *(const ushort4*)(tbase + ((size_t)rloc << 9) + laneoff);
        rv[r] = __builtin_nontemporal_load(
                    &((const f32x4*)rf)[(size_t)(wrow0 + r) * 64 + lane]);
#pragma unroll
        for (int k = 0; k < KNB; ++k)
            g[r][k] = *(const ushort4*)(tbase + ((size_t)(unsigned)nbs[r][k] << 9) + laneoff);
    }
    SCHED_FENCE();   // nothing above may sink below: all 44 loads stay in flight

    // ---- phase C: weights (only needs d -> overlaps gather flight) ----
    float wk[4][KNB];
#pragma unroll
    for (int r = 0; r < 4; ++r) {
        float mn = d[r][0];
#pragma unroll
        for (int k = 1; k < KNB; ++k) mn = fminf(mn, d[r][k]);
        float e[KNB]; float sum = 0.f;
#pragma unroll
        for (int k = 0; k < KNB; ++k) { e[k] = __expf(mn - d[r][k]); sum += e[k]; }
        const float inv = 0.05f / sum;
#pragma unroll
        for (int k = 0; k < KNB; ++k) wk[r][k] = e[k] * inv;
    }

    // ---- phase D: blend + store ----
#pragma unroll
    for (int r = 0; r < 4; ++r) {
        f32x4 acc;
        acc.x = 0.95f * bf16_to_f32(c0[r].x) + rv[r].x;
        acc.y = 0.95f * bf16_to_f32(c0[r].y) + rv[r].y;
        acc.z = 0.95f * bf16_to_f32(c0[r].z) + rv[r].z;
        acc.w = 0.95f * bf16_to_f32(c0[r].w) + rv[r].w;
#pragma unroll
        for (int k = 0; k < KNB; ++k) {
            const float wkk = wk[r][k];
            acc.x += wkk * bf16_to_f32(g[r][k].x);
            acc.y += wkk * bf16_to_f32(g[r][k].y);
            acc.z += wkk * bf16_to_f32(g[r][k].z);
            acc.w += wkk * bf16_to_f32(g[r][k].w);
        }
        __builtin_nontemporal_store(
            acc, &((f32x4*)out)[(size_t)(wrow0 + r) * 64 + lane]);
    }
}

extern "C" void kernel_launch(void* const* d_in, const int* in_sizes, int n_in,
                              void* d_out, int out_size, void* d_ws, size_t ws_size,
                              hipStream_t stream) {
    const float* x    = (const float*)d_in[0];
    const float* dist = (const float*)d_in[1];
    const int*   idx  = (const int*)d_in[2];
    const float* rf   = (const float*)d_in[3];
    const float* w1   = (const float*)d_in[4];
    const float* w2   = (const float*)d_in[5];
    const float* bias = (const float*)d_in[6];
    float* out = (float*)d_out;

    ushort_t* t  = (ushort_t*)d_ws;                                   // 32 MiB bf16 t
    ushort_t* xb = (ushort_t*)((char*)d_ws + (size_t)NROWS * CH * 2); // 32 MiB bf16 x

    pm_conv  <<<NBLK_CONV, 256, 0, stream>>>((const f32x4*)x, (uint4*)xb);
    pm_stage1<<<NBLK_S1,   256, 0, stream>>>(xb, dist, idx, w1, w2, bias, t);
    pm_stage2<<<NBLK_S2,   256, 0, stream>>>(t, dist, idx, rf, out);
}